// Round 5
// baseline (184.632 us; speedup 1.0000x reference)
//
#include <hip/hip_runtime.h>
#include <math.h>

#define NN   2048
#define BB   16

// ws layout (float offsets)
#define WS_X0   0
#define WS_QT   65536
#define WS_KT   131072
#define WS_VT   196608
#define WS_PART 262144   // [32 slot][4 h][4 kslice][12]: o[8], ssum, pad
#define WS_GI   268800   // [16 edge][96]
#define WS_FLAG 270336   // 128 uint flags (zeroed by kernel A)

__device__ __forceinline__ float sigmoidf_(float x) { return 1.0f / (1.0f + __expf(-x)); }
__device__ __forceinline__ float tanhf_(float x) {
    float ex = __expf(2.0f * x);
    return 1.0f - 2.0f / (ex + 1.0f);
}
__device__ __forceinline__ float dot4_(float4 a, float4 b) {
    return a.x*b.x + a.y*b.y + a.z*b.z + a.w*b.w;
}

// ---------------------------------------------------------------------------
// kA: 256 blocks. All: x0 = nf@Wemb^T+b ; qkv = x0@Wqkv^T+b (head-major).
//     blocks 0..15: message path for edge bx -> gi[bx][96].
//     blocks 16..79: memory -> out[16..] bulk copy.
//     block 255: zero kB's flag array.
// All staging batched: global loads into regs first, then LDS writes.
// ---------------------------------------------------------------------------
__global__ __launch_bounds__(256) void kA_embed_qkv_msg(
    const float* __restrict__ nf, const float* __restrict__ Wemb, const float* __restrict__ bemb,
    const float* __restrict__ Wqkv, const float* __restrict__ bqkv,
    const float* __restrict__ mem, const int* __restrict__ src, const int* __restrict__ dst,
    const float* __restrict__ ef,
    const float* __restrict__ Wm1, const float* __restrict__ bm1,
    const float* __restrict__ Wm2, const float* __restrict__ bm2,
    const float* __restrict__ Wih, const float* __restrict__ bih,
    float* __restrict__ ws, float* __restrict__ out)
{
    // node path LDS (stride 130: float2 rows, 2-way bank aliasing = free)
    __shared__ float We_s[32 * 130];
    __shared__ float nf_s[8 * 130];
    __shared__ float x0_s[8 * 33];
    __shared__ float Wq_s[96 * 33];
    // message path LDS (single edge per block)
    __shared__ __align__(16) float Wm1_s[2144];
    __shared__ float Wm2_s[32 * 33];
    __shared__ float Wih_s[96 * 33];
    __shared__ float min_s[67];
    __shared__ float mr_s[32];
    __shared__ float msg_s[32];

    const int t = threadIdx.x, bx = blockIdx.x;
    const bool domsg = (bx < 16);

    // ---- batched reg loads (all independent; one latency round) ----
    float4 rA[4], rB[3], rC;
    #pragma unroll
    for (int k = 0; k < 4; ++k) rA[k] = ((const float4*)Wemb)[t + 256 * k];
    #pragma unroll
    for (int k = 0; k < 3; ++k) rB[k] = ((const float4*)Wqkv)[t + 256 * k];
    rC = ((const float4*)nf)[bx * 256 + t];

    float4 rm1[3], rm2v, rih[3];
    float rminv = 0.f;
    if (domsg) {
        #pragma unroll
        for (int k = 0; k < 3; ++k) {
            int idx = t + 256 * k;
            rm1[k] = (idx < 536) ? ((const float4*)Wm1)[idx] : make_float4(0,0,0,0);
        }
        rm2v = ((const float4*)Wm2)[t];
        #pragma unroll
        for (int k = 0; k < 3; ++k) rih[k] = ((const float4*)Wih)[t + 256 * k];
        if (t < 67) {
            const int e = bx;
            rminv = (t < 32) ? mem[src[e] * 32 + t]
                  : (t < 64) ? mem[dst[e] * 32 + (t - 32)]
                             : ef[e * 3 + (t - 64)];
        }
    }

    // side jobs
    if (bx == 255 && t < 128) ((unsigned*)(ws + WS_FLAG))[t] = 0u;
    if (bx >= 16 && bx < 80) {
        int g = (bx - 16) * 256 + t;
        ((float4*)(out + 16))[g] = ((const float4*)mem)[g];
    }

    // ---- LDS writes ----
    #pragma unroll
    for (int k = 0; k < 4; ++k) {
        int idx = t + 256 * k;
        int r = idx >> 5, c = (idx & 31) * 4;
        We_s[r * 130 + c] = rA[k].x; We_s[r * 130 + c + 1] = rA[k].y;
        We_s[r * 130 + c + 2] = rA[k].z; We_s[r * 130 + c + 3] = rA[k].w;
    }
    #pragma unroll
    for (int k = 0; k < 3; ++k) {
        int idx = t + 256 * k;
        int r = idx >> 3, c = (idx & 7) * 4;
        Wq_s[r * 33 + c] = rB[k].x; Wq_s[r * 33 + c + 1] = rB[k].y;
        Wq_s[r * 33 + c + 2] = rB[k].z; Wq_s[r * 33 + c + 3] = rB[k].w;
    }
    {
        int r = t >> 5, c = (t & 31) * 4;
        nf_s[r * 130 + c] = rC.x; nf_s[r * 130 + c + 1] = rC.y;
        nf_s[r * 130 + c + 2] = rC.z; nf_s[r * 130 + c + 3] = rC.w;
    }
    if (domsg) {
        #pragma unroll
        for (int k = 0; k < 3; ++k) {
            int idx = t + 256 * k;
            if (idx < 536) ((float4*)Wm1_s)[idx] = rm1[k];
        }
        { int r = t >> 3, c = (t & 7) * 4;
          Wm2_s[r * 33 + c] = rm2v.x; Wm2_s[r * 33 + c + 1] = rm2v.y;
          Wm2_s[r * 33 + c + 2] = rm2v.z; Wm2_s[r * 33 + c + 3] = rm2v.w; }
        #pragma unroll
        for (int k = 0; k < 3; ++k) {
            int idx = t + 256 * k;
            int r = idx >> 3, c = (idx & 7) * 4;
            Wih_s[r * 33 + c] = rih[k].x; Wih_s[r * 33 + c + 1] = rih[k].y;
            Wih_s[r * 33 + c + 2] = rih[k].z; Wih_s[r * 33 + c + 3] = rih[k].w;
        }
        if (t < 67) min_s[t] = rminv;
    }
    __syncthreads();

    const int j = t >> 5, o = t & 31;
    const int n = bx * 8 + j;

    // x0 = nf @ Wemb^T + b
    float acc = bemb[o];
    {
        const float2* Wr = (const float2*)&We_s[o * 130];
        const float2* Nr = (const float2*)&nf_s[j * 130];
        float sx = 0.f, sy = 0.f;
        #pragma unroll 16
        for (int i = 0; i < 64; ++i) {
            float2 w = Wr[i], x = Nr[i];
            sx += w.x * x.x; sy += w.y * x.y;
        }
        acc += sx + sy;
    }
    x0_s[j * 33 + o] = acc;
    ws[WS_X0 + n * 32 + o] = acc;
    // msg stage 1: mr = relu(Wm1 @ min)
    if (domsg && t < 32) {
        float a1 = bm1[t];
        for (int i = 0; i < 67; ++i) a1 += Wm1_s[t * 67 + i] * min_s[i];
        mr_s[t] = fmaxf(a1, 0.f);
    }
    __syncthreads();

    // qkv
    #pragma unroll
    for (int c = 0; c < 3; ++c) {
        int oo = c * 32 + o;
        float a2 = bqkv[oo];
        #pragma unroll 8
        for (int i = 0; i < 32; ++i) a2 += Wq_s[oo * 33 + i] * x0_s[j * 33 + i];
        int h = o >> 3, d = o & 7;
        float* base = ws + (c == 0 ? WS_QT : (c == 1 ? WS_KT : WS_VT));
        base[h * 16384 + n * 8 + d] = a2;  // [h][n][d]
    }
    // msg stage 2: msg = Wm2 @ mr
    if (domsg && t < 32) {
        float a2 = bm2[t];
        #pragma unroll 8
        for (int i = 0; i < 32; ++i) a2 += Wm2_s[t * 33 + i] * mr_s[i];
        msg_s[t] = a2;
    }
    __syncthreads();

    // msg stage 3: gi = Wih @ msg + bih
    if (domsg && t < 96) {
        float a3 = bih[t];
        #pragma unroll 8
        for (int i = 0; i < 32; ++i) a3 += Wih_s[t * 33 + i] * msg_s[i];
        ws[WS_GI + bx * 96 + t] = a3;  // [e][96]
    }
}

// ---------------------------------------------------------------------------
// kB: 128 blocks. Every block: attention for (slot=bx>>2, ks=bx&3), then
// threadfence + flag. Block 0: preloads all post/scan weights into regs at
// entry (latency hidden under attention), spins on the 128 flags, then runs
// the full post-transformer + edge-head + GRU scan.
// ---------------------------------------------------------------------------
__global__ __launch_bounds__(256, 1) void kB_attn_post_scan(
    const int* __restrict__ src, const int* __restrict__ dst,
    const float* __restrict__ mem,
    const float* __restrict__ Wo, const float* __restrict__ bo,
    const float* __restrict__ g1, const float* __restrict__ be1,
    const float* __restrict__ Wf1, const float* __restrict__ bf1,
    const float* __restrict__ Wf2, const float* __restrict__ bf2,
    const float* __restrict__ g2, const float* __restrict__ be2,
    const float* __restrict__ Wscn, const float* __restrict__ bscn,
    const float* __restrict__ gscn, const float* __restrict__ bescn,
    const float* __restrict__ Whh, const float* __restrict__ bhh,
    const float* __restrict__ We1, const float* __restrict__ be1e,
    const float* __restrict__ We2, const float* __restrict__ be2e,
    const float* __restrict__ We3, const float* __restrict__ be3,
    float* __restrict__ ws, float* __restrict__ out)
{
    __shared__ float Wo_s[32 * 33];
    __shared__ float Wf1_s[64 * 33];
    __shared__ float Wf2_s[32 * 65];
    __shared__ float Ws_s[16 * 33];
    __shared__ float arow[32 * 33];
    __shared__ float x1s[32 * 33];
    __shared__ float fs[32 * 65];
    __shared__ float sout_s[32 * 17];
    __shared__ float We1_s[32 * 33];
    __shared__ float We2_s[16 * 33];
    __shared__ float gi_s[16 * 97];
    __shared__ __align__(16) float slots[32 * 36];
    __shared__ int nid_s[32], fid_s[32], last_s[32];

    const int t = threadIdx.x, bx = blockIdx.x;
    unsigned* flags = (unsigned*)(ws + WS_FLAG);

    // ---- block 0: issue ALL post/scan weight loads now (hide under attn) ----
    float4 w1[8], w2[8], w3[8];
    float b1 = 0.f, b2 = 0.f, b3 = 0.f;
    float4 rWo, rF1a, rF1b, rF2a, rF2b, rE1, rWs, rE2, rG0, rG1;
    if (bx == 0) {
        if (t < 64) {
            const int r2 = (t < 32) ? t + 64 : t - 32;
            const int r3 = t + 32;
            #pragma unroll
            for (int c = 0; c < 8; ++c) {
                w1[c] = ((const float4*)Whh)[t * 8 + c];
                w2[c] = ((const float4*)Whh)[r2 * 8 + c];
                w3[c] = ((const float4*)Whh)[r3 * 8 + c];
            }
            b1 = bhh[t]; b2 = bhh[r2]; b3 = bhh[r3];
        }
        rWo  = ((const float4*)Wo)[t];
        rF1a = ((const float4*)Wf1)[t]; rF1b = ((const float4*)Wf1)[t + 256];
        rF2a = ((const float4*)Wf2)[t]; rF2b = ((const float4*)Wf2)[t + 256];
        rE1  = ((const float4*)We1)[t];
        rG0  = ((const float4*)(ws + WS_GI))[t];
        if (t < 128) {
            rWs = ((const float4*)Wscn)[t];
            rE2 = ((const float4*)We2)[t];
            rG1 = ((const float4*)(ws + WS_GI))[t + 256];
        }
        if (t < 32) nid_s[t] = (t & 1) ? dst[t >> 1] : src[t >> 1];
    }

    // ---- attention (all 128 blocks) ----
    {
        const int s  = bx >> 2;
        const int ks = bx & 3;
        const int h  = t >> 6;
        const int l  = t & 63;
        const int e = s >> 1;
        const int n = (s & 1) ? dst[e] : src[e];

        const float* qg = ws + WS_QT + h * 16384 + n * 8;
        const float4 qa  = *(const float4*)qg;
        const float4 qb4 = *(const float4*)(qg + 4);
        const float* kbase = ws + WS_KT + h * 16384;
        const float* vbase = ws + WS_VT + h * 16384;

        float4 oa = make_float4(0.f, 0.f, 0.f, 0.f);
        float4 ob = make_float4(0.f, 0.f, 0.f, 0.f);
        float ssum = 0.f;
        const float scale = 0.35355339059327373f;  // 1/sqrt(8)

        #pragma unroll
        for (int i = 0; i < 8; ++i) {
            const int key = ks * 512 + i * 64 + l;
            const float4 ka = *(const float4*)(kbase + key * 8);
            const float4 kb = *(const float4*)(kbase + key * 8 + 4);
            const float sc = (dot4_(qa, ka) + dot4_(qb4, kb)) * scale;
            const float p = __expf(sc);
            ssum += p;
            const float4 va = *(const float4*)(vbase + key * 8);
            const float4 vb = *(const float4*)(vbase + key * 8 + 4);
            oa.x += p * va.x; oa.y += p * va.y; oa.z += p * va.z; oa.w += p * va.w;
            ob.x += p * vb.x; ob.y += p * vb.y; ob.z += p * vb.z; ob.w += p * vb.w;
        }
        #pragma unroll
        for (int m = 1; m <= 32; m <<= 1) {
            ssum += __shfl_xor(ssum, m);
            oa.x += __shfl_xor(oa.x, m); oa.y += __shfl_xor(oa.y, m);
            oa.z += __shfl_xor(oa.z, m); oa.w += __shfl_xor(oa.w, m);
            ob.x += __shfl_xor(ob.x, m); ob.y += __shfl_xor(ob.y, m);
            ob.z += __shfl_xor(ob.z, m); ob.w += __shfl_xor(ob.w, m);
        }
        if (l == 0) {
            float* p = ws + WS_PART + ((s * 4 + h) * 4 + ks) * 12;
            *(float4*)p       = oa;
            *(float4*)(p + 4) = ob;
            p[8] = ssum;
        }
    }
    __threadfence();                       // release partials (device scope)
    if (t == 0) atomicExch(&flags[bx], 1u);
    if (bx != 0) return;

    // ---- block 0: wait for all 128 partials ----
    if (t < 128) {
        while (atomicAdd(&flags[t], 0u) == 0u) { __builtin_amdgcn_s_sleep(8); }
    }
    __syncthreads();
    __threadfence();                       // acquire

    const int j0 = t >> 5, o = t & 31;

    // ---- LDS writes of preloaded weights ----
    { int r = t >> 3, c = (t & 7) * 4;
      Wo_s[r * 33 + c] = rWo.x; Wo_s[r * 33 + c + 1] = rWo.y;
      Wo_s[r * 33 + c + 2] = rWo.z; Wo_s[r * 33 + c + 3] = rWo.w;
      We1_s[r * 33 + c] = rE1.x; We1_s[r * 33 + c + 1] = rE1.y;
      We1_s[r * 33 + c + 2] = rE1.z; We1_s[r * 33 + c + 3] = rE1.w;
      Wf1_s[r * 33 + c] = rF1a.x; Wf1_s[r * 33 + c + 1] = rF1a.y;
      Wf1_s[r * 33 + c + 2] = rF1a.z; Wf1_s[r * 33 + c + 3] = rF1a.w;
      int r2 = (t + 256) >> 3, c2 = ((t + 256) & 7) * 4;
      Wf1_s[r2 * 33 + c2] = rF1b.x; Wf1_s[r2 * 33 + c2 + 1] = rF1b.y;
      Wf1_s[r2 * 33 + c2 + 2] = rF1b.z; Wf1_s[r2 * 33 + c2 + 3] = rF1b.w; }
    { int r = t >> 4, c = (t & 15) * 4;
      Wf2_s[r * 65 + c] = rF2a.x; Wf2_s[r * 65 + c + 1] = rF2a.y;
      Wf2_s[r * 65 + c + 2] = rF2a.z; Wf2_s[r * 65 + c + 3] = rF2a.w;
      int r2 = (t + 256) >> 4, c2 = ((t + 256) & 15) * 4;
      Wf2_s[r2 * 65 + c2] = rF2b.x; Wf2_s[r2 * 65 + c2 + 1] = rF2b.y;
      Wf2_s[r2 * 65 + c2 + 2] = rF2b.z; Wf2_s[r2 * 65 + c2 + 3] = rF2b.w; }
    { int f = 4 * t, e = f / 96, off = f - e * 96;
      gi_s[e * 97 + off] = rG0.x; gi_s[e * 97 + off + 1] = rG0.y;
      gi_s[e * 97 + off + 2] = rG0.z; gi_s[e * 97 + off + 3] = rG0.w; }
    if (t < 128) {
        int r = t >> 3, c = (t & 7) * 4;
        Ws_s[r * 33 + c] = rWs.x; Ws_s[r * 33 + c + 1] = rWs.y;
        Ws_s[r * 33 + c + 2] = rWs.z; Ws_s[r * 33 + c + 3] = rWs.w;
        We2_s[r * 33 + c] = rE2.x; We2_s[r * 33 + c + 1] = rE2.y;
        We2_s[r * 33 + c + 2] = rE2.z; We2_s[r * 33 + c + 3] = rE2.w;
        int f = 4 * (t + 256), e2 = f / 96, off = f - e2 * 96;
        gi_s[e2 * 97 + off] = rG1.x; gi_s[e2 * 97 + off + 1] = rG1.y;
        gi_s[e2 * 97 + off + 2] = rG1.z; gi_s[e2 * 97 + off + 3] = rG1.w;
    }

    // attn-partial combine + x0 gather (pre-barrier)
    float x0v[4];
    #pragma unroll
    for (int si = 0; si < 4; ++si) {
        const int jj = si * 8 + j0;
        const int ej = jj >> 1;
        const int n = (jj & 1) ? dst[ej] : src[ej];
        const int h = o >> 3, d = o & 7;
        float num = 0.f, den = 0.f;
        #pragma unroll
        for (int ks = 0; ks < 4; ++ks) {
            const float* p = ws + WS_PART + ((jj * 4 + h) * 4 + ks) * 12;
            num += p[d];
            den += p[8];
        }
        arow[jj * 33 + o] = num / den;
        x0v[si] = ws[WS_X0 + n * 32 + o];
    }
    __syncthreads();

    // fid/last
    if (t < 32) {
        int me = nid_s[t], f = t;
        for (int j2 = 0; j2 < t; ++j2) if (nid_s[j2] == me) { f = j2; break; }
        fid_s[t] = f;
        int isl = 1;
        for (int j2 = t + 1; j2 < 32; ++j2) if (nid_s[j2] == me) { isl = 0; break; }
        last_s[t] = isl;
    }
    __syncthreads();

    // slot memory gather (completes before GRU)
    #pragma unroll
    for (int k = 0; k < 4; ++k) {
        int j2 = j0 + 8 * k;
        if (fid_s[j2] == j2) slots[j2 * 36 + o] = mem[nid_s[j2] * 32 + o];
    }

    // ---- A1: Wo GEMM + residual + LN1 -> x1s ----
    #pragma unroll
    for (int si = 0; si < 4; ++si) {
        const int jj = si * 8 + j0;
        float a = bo[o];
        #pragma unroll 8
        for (int i = 0; i < 32; ++i) a += Wo_s[o * 33 + i] * arow[jj * 33 + i];
        float t1 = x0v[si] + a;
        float mu = t1;
        #pragma unroll
        for (int m = 16; m >= 1; m >>= 1) mu += __shfl_xor(mu, m, 32);
        mu *= (1.f / 32.f);
        float dv = t1 - mu;
        float var = dv * dv;
        #pragma unroll
        for (int m = 16; m >= 1; m >>= 1) var += __shfl_xor(var, m, 32);
        var *= (1.f / 32.f);
        x1s[jj * 33 + o] = dv * rsqrtf(var + 1e-5f) * g1[o] + be1[o];
    }
    __syncthreads();

    // ---- A2: FFN1 + gelu -> fs ----
    #pragma unroll
    for (int si = 0; si < 4; ++si) {
        const int jj = si * 8 + j0;
        #pragma unroll
        for (int c = 0; c < 2; ++c) {
            int oo = c * 32 + o;
            float f = bf1[oo];
            #pragma unroll 8
            for (int i = 0; i < 32; ++i) f += Wf1_s[oo * 33 + i] * x1s[jj * 33 + i];
            fs[jj * 65 + oo] = 0.5f * f * (1.f + erff(f * 0.70710678118654752f));
        }
    }
    __syncthreads();

    // ---- A3: FFN2 + residual + LN2 -> x1s ----
    #pragma unroll
    for (int si = 0; si < 4; ++si) {
        const int jj = si * 8 + j0;
        float f2 = bf2[o];
        #pragma unroll 8
        for (int i = 0; i < 64; ++i) f2 += Wf2_s[o * 65 + i] * fs[jj * 65 + i];
        float t2 = x1s[jj * 33 + o] + f2;
        float mu2 = t2;
        #pragma unroll
        for (int m = 16; m >= 1; m >>= 1) mu2 += __shfl_xor(mu2, m, 32);
        mu2 *= (1.f / 32.f);
        float dv2 = t2 - mu2;
        float var2 = dv2 * dv2;
        #pragma unroll
        for (int m = 16; m >= 1; m >>= 1) var2 += __shfl_xor(var2, m, 32);
        var2 *= (1.f / 32.f);
        x1s[jj * 33 + o] = dv2 * rsqrtf(var2 + 1e-5f) * g2[o] + be2[o];
    }
    __syncthreads();

    // ---- A4: SCN + LN(16) + relu -> sout_s ----
    if (o < 16) {
        #pragma unroll
        for (int si = 0; si < 4; ++si) {
            const int jj = si * 8 + j0;
            float sc = bscn[o];
            #pragma unroll 8
            for (int i = 0; i < 32; ++i) sc += Ws_s[o * 33 + i] * x1s[jj * 33 + i];
            float m16 = sc;
            #pragma unroll
            for (int m = 8; m >= 1; m >>= 1) m16 += __shfl_xor(m16, m, 16);
            m16 *= (1.f / 16.f);
            float d16 = sc - m16;
            float v16 = d16 * d16;
            #pragma unroll
            for (int m = 8; m >= 1; m >>= 1) v16 += __shfl_xor(v16, m, 16);
            v16 *= (1.f / 16.f);
            float sv = d16 * rsqrtf(v16 + 1e-5f) * gscn[o] + bescn[o];
            sout_s[jj * 17 + o] = fmaxf(sv, 0.f);
        }
    }
    __syncthreads();

    // ---- A5: edge cat ----
    #pragma unroll
    for (int k = 0; k < 2; ++k) {
        int idx = t + 256 * k;
        int e = idx >> 5, i = idx & 31;
        arow[e * 33 + i] = (i < 16) ? sout_s[(2 * e) * 17 + i]
                                    : sout_s[(2 * e + 1) * 17 + (i - 16)];
    }
    __syncthreads();

    // ---- A6: h1 ----
    #pragma unroll
    for (int k = 0; k < 2; ++k) {
        int e = j0 + 8 * k;
        float acc = be1e[o];
        #pragma unroll 8
        for (int i = 0; i < 32; ++i) acc += We1_s[o * 33 + i] * arow[e * 33 + i];
        fs[e * 33 + o] = fmaxf(acc, 0.f);
    }
    __syncthreads();

    // ---- A7: h2 ----
    {
        int e = t >> 4, o2 = t & 15;
        float acc = be2e[o2];
        #pragma unroll 8
        for (int i = 0; i < 32; ++i) acc += We2_s[o2 * 33 + i] * fs[e * 33 + i];
        fs[600 + e * 17 + o2] = fmaxf(acc, 0.f);
    }
    __syncthreads();

    // ---- A8: logits ----
    if (t < 16) {
        float acc = be3[0];
        #pragma unroll
        for (int i = 0; i < 16; ++i) acc += We3[i] * fs[600 + t * 17 + i];
        out[t] = acc;
    }
    __syncthreads();

    // ---- GRU scan: wave 0 ----
    if (t < 64) {
        const bool lowhalf = (t < 32);
        for (int e = 0; e < 16; ++e) {
            const int js = 2 * e, jd = 2 * e + 1;
            const int ss = fid_s[js], sd = fid_s[jd];
            const bool same = (nid_s[js] == nid_s[jd]);
            const int npass = same ? 2 : 1;
            for (int pass = 0; pass < npass; ++pass) {
                const bool do_src = (!same) || (pass == 0);
                const bool do_dst = (!same) || (pass == 1);
                float acc1 = b1, acc2 = b2, acc3 = b3;
                #pragma unroll
                for (int c = 0; c < 8; ++c) {
                    const float4 hs4 = *(const float4*)&slots[ss * 36 + 4 * c];
                    const float4 hd4 = *(const float4*)&slots[sd * 36 + 4 * c];
                    acc1 += dot4_(w1[c], hs4);
                    const float4 hm = lowhalf ? hs4 : hd4;
                    acc2 += dot4_(w2[c], hm);
                    acc3 += dot4_(w3[c], hd4);
                }
                const float shv = __shfl_xor(lowhalf ? acc3 : acc1, 32);
                const float hr = lowhalf ? acc1 : acc2;
                const float hz = shv;
                const float hn = lowhalf ? acc2 : acc3;
                const float ir  = gi_s[e * 97 + o];
                const float iz  = gi_s[e * 97 + 32 + o];
                const float inn = gi_s[e * 97 + 64 + o];
                const float r = sigmoidf_(ir + hr);
                const float z = sigmoidf_(iz + hz);
                const float nn = tanhf_(inn + r * hn);
                const int slot = lowhalf ? ss : sd;
                const float hold = slots[slot * 36 + o];
                const float hnew = (1.f - z) * nn + z * hold;
                const bool wr = lowhalf ? do_src : do_dst;
                if (wr) slots[slot * 36 + o] = hnew;
                __threadfence_block();
            }
        }
    }
    __syncthreads();

    // ---- writeback ----
    #pragma unroll
    for (int k = 0; k < 4; ++k) {
        int j2 = j0 + 8 * k;
        if (last_s[j2]) out[16 + nid_s[j2] * 32 + o] = slots[fid_s[j2] * 36 + o];
    }
}

// ---------------------------------------------------------------------------
extern "C" void kernel_launch(void* const* d_in, const int* in_sizes, int n_in,
                              void* d_out, int out_size, void* d_ws, size_t ws_size,
                              hipStream_t stream)
{
    (void)in_sizes; (void)n_in; (void)out_size; (void)ws_size;
    const int*   src   = (const int*)d_in[0];
    const int*   dst   = (const int*)d_in[1];
    const float* ef    = (const float*)d_in[2];
    const float* nf    = (const float*)d_in[4];
    const float* mem   = (const float*)d_in[6];
    const float* Wemb  = (const float*)d_in[7];
    const float* bemb  = (const float*)d_in[8];
    const float* Wqkv  = (const float*)d_in[9];
    const float* bqkv  = (const float*)d_in[10];
    const float* Wo    = (const float*)d_in[11];
    const float* bo    = (const float*)d_in[12];
    const float* g1    = (const float*)d_in[13];
    const float* be1   = (const float*)d_in[14];
    const float* g2    = (const float*)d_in[15];
    const float* be2   = (const float*)d_in[16];
    const float* Wf1   = (const float*)d_in[17];
    const float* bf1   = (const float*)d_in[18];
    const float* Wf2   = (const float*)d_in[19];
    const float* bf2   = (const float*)d_in[20];
    const float* Wscn  = (const float*)d_in[21];
    const float* bscn  = (const float*)d_in[22];
    const float* gscn  = (const float*)d_in[23];
    const float* bescn = (const float*)d_in[24];
    const float* We1   = (const float*)d_in[25];
    const float* be1e  = (const float*)d_in[26];
    const float* We2   = (const float*)d_in[27];
    const float* be2e  = (const float*)d_in[28];
    const float* We3   = (const float*)d_in[29];
    const float* be3   = (const float*)d_in[30];
    const float* Wih   = (const float*)d_in[31];
    const float* bih   = (const float*)d_in[32];
    const float* Whh   = (const float*)d_in[33];
    const float* bhh   = (const float*)d_in[34];
    const float* Wm1   = (const float*)d_in[35];
    const float* bm1   = (const float*)d_in[36];
    const float* Wm2   = (const float*)d_in[37];
    const float* bm2   = (const float*)d_in[38];
    float* out = (float*)d_out;
    float* ws  = (float*)d_ws;

    hipLaunchKernelGGL(kA_embed_qkv_msg, dim3(256), dim3(256), 0, stream,
        nf, Wemb, bemb, Wqkv, bqkv, mem, src, dst, ef, Wm1, bm1, Wm2, bm2, Wih, bih, ws, out);
    hipLaunchKernelGGL(kB_attn_post_scan, dim3(128), dim3(256), 0, stream,
        src, dst, mem, Wo, bo, g1, be1, Wf1, bf1, Wf2, bf2, g2, be2,
        Wscn, bscn, gscn, bescn, Whh, bhh, We1, be1e, We2, be2e, We3, be3, ws, out);
}

// Round 6
// 174.239 us; speedup vs baseline: 1.0596x; 1.0596x over previous
//
#include <hip/hip_runtime.h>
#include <math.h>

#define NN   2048
#define BB   16

// ws layout (float offsets)
#define WS_X0   0
#define WS_QT   65536
#define WS_KT   131072
#define WS_VT   196608
#define WS_PART 262144   // [32 slot][4 h][4 kslice][12]: o[8], ssum, pad
#define WS_GI   268800   // [16 edge][96]

// bias_s layout (float offsets)
#define B_BO    0
#define B_G1    32
#define B_BE1   64
#define B_G2    96
#define B_BE2   128
#define B_BF1   160   // 64
#define B_BF2   224
#define B_BSCN  256   // 16
#define B_GSCN  272
#define B_BESCN 288
#define B_BE1E  304   // 32
#define B_BE2E  336   // 16
#define B_WE3   352   // 16
#define B_BE3   368

__device__ __forceinline__ float sigmoidf_(float x) { return 1.0f / (1.0f + __expf(-x)); }
__device__ __forceinline__ float tanhf_(float x) {
    float ex = __expf(2.0f * x);
    return 1.0f - 2.0f / (ex + 1.0f);
}
__device__ __forceinline__ float dot4_(float4 a, float4 b) {
    return a.x*b.x + a.y*b.y + a.z*b.z + a.w*b.w;
}

// ---------------------------------------------------------------------------
// K1: 256 blocks. All: x0 = nf@Wemb^T+b ; qkv = x0@Wqkv^T+b (head-major).
//     blocks 0..15: message path for edge bx -> gi[bx][96].
//     blocks 16..79: memory -> out[16..] bulk copy.
// ---------------------------------------------------------------------------
__global__ __launch_bounds__(256) void k1_embed_qkv_msg(
    const float* __restrict__ nf, const float* __restrict__ Wemb, const float* __restrict__ bemb,
    const float* __restrict__ Wqkv, const float* __restrict__ bqkv,
    const float* __restrict__ mem, const int* __restrict__ src, const int* __restrict__ dst,
    const float* __restrict__ ef,
    const float* __restrict__ Wm1, const float* __restrict__ bm1,
    const float* __restrict__ Wm2, const float* __restrict__ bm2,
    const float* __restrict__ Wih, const float* __restrict__ bih,
    float* __restrict__ ws, float* __restrict__ out)
{
    __shared__ float We_s[32 * 130];
    __shared__ float nf_s[8 * 130];
    __shared__ float x0_s[8 * 33];
    __shared__ float Wq_s[96 * 33];
    __shared__ __align__(16) float Wm1_s[2144];
    __shared__ float Wm2_s[32 * 33];
    __shared__ float Wih_s[96 * 33];
    __shared__ float min_s[67];
    __shared__ float mr_s[32];
    __shared__ float msg_s[32];

    const int t = threadIdx.x, bx = blockIdx.x;
    const bool domsg = (bx < 16);

    // ---- batched reg loads (independent; one latency round) ----
    float4 rA[4], rB[3], rC;
    #pragma unroll
    for (int k = 0; k < 4; ++k) rA[k] = ((const float4*)Wemb)[t + 256 * k];
    #pragma unroll
    for (int k = 0; k < 3; ++k) rB[k] = ((const float4*)Wqkv)[t + 256 * k];
    rC = ((const float4*)nf)[bx * 256 + t];

    float4 rm1[3], rm2v, rih[3];
    float rminv = 0.f;
    if (domsg) {
        #pragma unroll
        for (int k = 0; k < 3; ++k) {
            int idx = t + 256 * k;
            rm1[k] = (idx < 536) ? ((const float4*)Wm1)[idx] : make_float4(0,0,0,0);
        }
        rm2v = ((const float4*)Wm2)[t];
        #pragma unroll
        for (int k = 0; k < 3; ++k) rih[k] = ((const float4*)Wih)[t + 256 * k];
        if (t < 67) {
            const int e = bx;
            rminv = (t < 32) ? mem[src[e] * 32 + t]
                  : (t < 64) ? mem[dst[e] * 32 + (t - 32)]
                             : ef[e * 3 + (t - 64)];
        }
    }

    if (bx >= 16 && bx < 80) {
        int g = (bx - 16) * 256 + t;
        ((float4*)(out + 16))[g] = ((const float4*)mem)[g];
    }

    // ---- LDS writes ----
    #pragma unroll
    for (int k = 0; k < 4; ++k) {
        int idx = t + 256 * k;
        int r = idx >> 5, c = (idx & 31) * 4;
        We_s[r * 130 + c] = rA[k].x; We_s[r * 130 + c + 1] = rA[k].y;
        We_s[r * 130 + c + 2] = rA[k].z; We_s[r * 130 + c + 3] = rA[k].w;
    }
    #pragma unroll
    for (int k = 0; k < 3; ++k) {
        int idx = t + 256 * k;
        int r = idx >> 3, c = (idx & 7) * 4;
        Wq_s[r * 33 + c] = rB[k].x; Wq_s[r * 33 + c + 1] = rB[k].y;
        Wq_s[r * 33 + c + 2] = rB[k].z; Wq_s[r * 33 + c + 3] = rB[k].w;
    }
    {
        int r = t >> 5, c = (t & 31) * 4;
        nf_s[r * 130 + c] = rC.x; nf_s[r * 130 + c + 1] = rC.y;
        nf_s[r * 130 + c + 2] = rC.z; nf_s[r * 130 + c + 3] = rC.w;
    }
    if (domsg) {
        #pragma unroll
        for (int k = 0; k < 3; ++k) {
            int idx = t + 256 * k;
            if (idx < 536) ((float4*)Wm1_s)[idx] = rm1[k];
        }
        { int r = t >> 3, c = (t & 7) * 4;
          Wm2_s[r * 33 + c] = rm2v.x; Wm2_s[r * 33 + c + 1] = rm2v.y;
          Wm2_s[r * 33 + c + 2] = rm2v.z; Wm2_s[r * 33 + c + 3] = rm2v.w; }
        #pragma unroll
        for (int k = 0; k < 3; ++k) {
            int idx = t + 256 * k;
            int r = idx >> 3, c = (idx & 7) * 4;
            Wih_s[r * 33 + c] = rih[k].x; Wih_s[r * 33 + c + 1] = rih[k].y;
            Wih_s[r * 33 + c + 2] = rih[k].z; Wih_s[r * 33 + c + 3] = rih[k].w;
        }
        if (t < 67) min_s[t] = rminv;
    }
    __syncthreads();

    const int j = t >> 5, o = t & 31;
    const int n = bx * 8 + j;

    float acc = bemb[o];
    {
        const float2* Wr = (const float2*)&We_s[o * 130];
        const float2* Nr = (const float2*)&nf_s[j * 130];
        float sx = 0.f, sy = 0.f;
        #pragma unroll 16
        for (int i = 0; i < 64; ++i) {
            float2 w = Wr[i], x = Nr[i];
            sx += w.x * x.x; sy += w.y * x.y;
        }
        acc += sx + sy;
    }
    x0_s[j * 33 + o] = acc;
    ws[WS_X0 + n * 32 + o] = acc;
    if (domsg && t < 32) {
        float a1 = bm1[t];
        for (int i = 0; i < 67; ++i) a1 += Wm1_s[t * 67 + i] * min_s[i];
        mr_s[t] = fmaxf(a1, 0.f);
    }
    __syncthreads();

    #pragma unroll
    for (int c = 0; c < 3; ++c) {
        int oo = c * 32 + o;
        float a2 = bqkv[oo];
        #pragma unroll 8
        for (int i = 0; i < 32; ++i) a2 += Wq_s[oo * 33 + i] * x0_s[j * 33 + i];
        int h = o >> 3, d = o & 7;
        float* base = ws + (c == 0 ? WS_QT : (c == 1 ? WS_KT : WS_VT));
        base[h * 16384 + n * 8 + d] = a2;  // [h][n][d]
    }
    if (domsg && t < 32) {
        float a2 = bm2[t];
        #pragma unroll 8
        for (int i = 0; i < 32; ++i) a2 += Wm2_s[t * 33 + i] * mr_s[i];
        msg_s[t] = a2;
    }
    __syncthreads();

    if (domsg && t < 96) {
        float a3 = bih[t];
        #pragma unroll 8
        for (int i = 0; i < 32; ++i) a3 += Wih_s[t * 33 + i] * msg_s[i];
        ws[WS_GI + bx * 96 + t] = a3;  // [e][96]
    }
}

// ---------------------------------------------------------------------------
// K2: attention for the 32 gathered query slots.
// grid 128 = slot(32) x kslice(4); block 256 = head(4) x 64 lanes.
// ---------------------------------------------------------------------------
__global__ __launch_bounds__(256) void k2_attn(
    const int* __restrict__ src, const int* __restrict__ dst,
    float* __restrict__ ws)
{
    const int t = threadIdx.x, bx = blockIdx.x;
    const int s  = bx >> 2;
    const int ks = bx & 3;
    const int h  = t >> 6;
    const int l  = t & 63;

    const int e = s >> 1;
    const int n = (s & 1) ? dst[e] : src[e];

    const float* qg = ws + WS_QT + h * 16384 + n * 8;
    const float4 qa  = *(const float4*)qg;
    const float4 qb4 = *(const float4*)(qg + 4);
    const float* kbase = ws + WS_KT + h * 16384;
    const float* vbase = ws + WS_VT + h * 16384;

    float4 oa = make_float4(0.f, 0.f, 0.f, 0.f);
    float4 ob = make_float4(0.f, 0.f, 0.f, 0.f);
    float ssum = 0.f;
    const float scale = 0.35355339059327373f;  // 1/sqrt(8)

    #pragma unroll
    for (int i = 0; i < 8; ++i) {
        const int key = ks * 512 + i * 64 + l;
        const float4 ka = *(const float4*)(kbase + key * 8);
        const float4 kb = *(const float4*)(kbase + key * 8 + 4);
        const float sc = (dot4_(qa, ka) + dot4_(qb4, kb)) * scale;
        const float p = __expf(sc);
        ssum += p;
        const float4 va = *(const float4*)(vbase + key * 8);
        const float4 vb = *(const float4*)(vbase + key * 8 + 4);
        oa.x += p * va.x; oa.y += p * va.y; oa.z += p * va.z; oa.w += p * va.w;
        ob.x += p * vb.x; ob.y += p * vb.y; ob.z += p * vb.z; ob.w += p * vb.w;
    }

    #pragma unroll
    for (int m = 1; m <= 32; m <<= 1) {
        ssum += __shfl_xor(ssum, m);
        oa.x += __shfl_xor(oa.x, m); oa.y += __shfl_xor(oa.y, m);
        oa.z += __shfl_xor(oa.z, m); oa.w += __shfl_xor(oa.w, m);
        ob.x += __shfl_xor(ob.x, m); ob.y += __shfl_xor(ob.y, m);
        ob.z += __shfl_xor(ob.z, m); ob.w += __shfl_xor(ob.w, m);
    }
    if (l == 0) {
        float* p = ws + WS_PART + ((s * 4 + h) * 4 + ks) * 12;
        *(float4*)p       = oa;
        *(float4*)(p + 4) = ob;
        p[8] = ssum;
    }
}

// ---------------------------------------------------------------------------
// K34: one block, 256 threads. All weights+biases batch-staged at entry.
// Transformer phases (x4 slot groups) -> edge head -> PARALLEL GRU scan:
// slots grouped into dependency rounds by node-occurrence index; each round
// processes up to 8 independent slots concurrently (4 waves x 2 slots/wave).
// ---------------------------------------------------------------------------
__global__ __launch_bounds__(256, 1) void k34_post_scan(
    const int* __restrict__ src, const int* __restrict__ dst,
    const float* __restrict__ mem,
    const float* __restrict__ Wo, const float* __restrict__ bo,
    const float* __restrict__ g1, const float* __restrict__ be1,
    const float* __restrict__ Wf1, const float* __restrict__ bf1,
    const float* __restrict__ Wf2, const float* __restrict__ bf2,
    const float* __restrict__ g2, const float* __restrict__ be2,
    const float* __restrict__ Wscn, const float* __restrict__ bscn,
    const float* __restrict__ gscn, const float* __restrict__ bescn,
    const float* __restrict__ Whh, const float* __restrict__ bhh,
    const float* __restrict__ We1, const float* __restrict__ be1e,
    const float* __restrict__ We2, const float* __restrict__ be2e,
    const float* __restrict__ We3, const float* __restrict__ be3,
    float* __restrict__ ws, float* __restrict__ out)
{
    __shared__ float Wo_s[32 * 33];
    __shared__ float Wf1_s[64 * 33];
    __shared__ float Wf2_s[32 * 65];
    __shared__ float Ws_s[16 * 33];
    __shared__ float We1_s[32 * 33];
    __shared__ float We2_s[16 * 33];
    __shared__ float arow[32 * 33];   // attn rows; later edge-cat (16x33)
    __shared__ float x1s[32 * 33];
    __shared__ float fs[32 * 65];     // FFN hidden; later h1/h2
    __shared__ float gi_s[16 * 97];
    __shared__ __align__(16) float slots[32 * 36];
    __shared__ float bias_s[384];
    __shared__ int nid_s[32], prev_s[32], round_s[32], last_s[32];
    __shared__ int list_s[32], cnt_s, maxr_s;

    const int t = threadIdx.x;
    const int j0 = t >> 5, o = t & 31;
    const int l = t & 63, w = t >> 6;
    const bool lowhalf = (l < 32);

    // ---- Whh + bhh into registers (ALL waves; one latency round) ----
    float4 w1[8], w2[8], w3[8];
    {
        const int r2 = lowhalf ? l + 64 : l - 32;
        const int r3 = l + 32;
        #pragma unroll
        for (int c = 0; c < 8; ++c) {
            w1[c] = ((const float4*)Whh)[l * 8 + c];
            w2[c] = ((const float4*)Whh)[r2 * 8 + c];
            w3[c] = ((const float4*)Whh)[r3 * 8 + c];
        }
    }
    const float b1 = bhh[l], b2 = bhh[lowhalf ? l + 64 : l - 32], b3 = bhh[l + 32];

    // ---- batched weight staging ----
    float4 rWo, rF1a, rF1b, rF2a, rF2b, rE1, rWs, rE2, rG0, rG1;
    rWo  = ((const float4*)Wo)[t];
    rF1a = ((const float4*)Wf1)[t]; rF1b = ((const float4*)Wf1)[t + 256];
    rF2a = ((const float4*)Wf2)[t]; rF2b = ((const float4*)Wf2)[t + 256];
    rE1  = ((const float4*)We1)[t];
    rG0  = ((const float4*)(ws + WS_GI))[t];
    if (t < 128) {
        rWs = ((const float4*)Wscn)[t];
        rE2 = ((const float4*)We2)[t];
        rG1 = ((const float4*)(ws + WS_GI))[t + 256];
    }
    // ---- biases straight to LDS (independent scalar loads) ----
    if (t < 32) {
        bias_s[B_BO + t]   = bo[t];
        bias_s[B_G1 + t]   = g1[t];
        bias_s[B_BE1 + t]  = be1[t];
        bias_s[B_G2 + t]   = g2[t];
        bias_s[B_BE2 + t]  = be2[t];
        bias_s[B_BF1 + t]  = bf1[t];
        bias_s[B_BF1 + 32 + t] = bf1[32 + t];
        bias_s[B_BF2 + t]  = bf2[t];
        bias_s[B_BE1E + t] = be1e[t];
        nid_s[t] = (t & 1) ? dst[t >> 1] : src[t >> 1];
    }
    if (t < 16) {
        bias_s[B_BSCN + t]  = bscn[t];
        bias_s[B_GSCN + t]  = gscn[t];
        bias_s[B_BESCN + t] = bescn[t];
        bias_s[B_BE2E + t]  = be2e[t];
        bias_s[B_WE3 + t]   = We3[t];
    }
    if (t == 0) bias_s[B_BE3] = be3[0];

    { int r = t >> 3, c = (t & 7) * 4;
      Wo_s[r * 33 + c] = rWo.x; Wo_s[r * 33 + c + 1] = rWo.y;
      Wo_s[r * 33 + c + 2] = rWo.z; Wo_s[r * 33 + c + 3] = rWo.w;
      We1_s[r * 33 + c] = rE1.x; We1_s[r * 33 + c + 1] = rE1.y;
      We1_s[r * 33 + c + 2] = rE1.z; We1_s[r * 33 + c + 3] = rE1.w;
      Wf1_s[r * 33 + c] = rF1a.x; Wf1_s[r * 33 + c + 1] = rF1a.y;
      Wf1_s[r * 33 + c + 2] = rF1a.z; Wf1_s[r * 33 + c + 3] = rF1a.w;
      int r2 = (t + 256) >> 3, c2 = ((t + 256) & 7) * 4;
      Wf1_s[r2 * 33 + c2] = rF1b.x; Wf1_s[r2 * 33 + c2 + 1] = rF1b.y;
      Wf1_s[r2 * 33 + c2 + 2] = rF1b.z; Wf1_s[r2 * 33 + c2 + 3] = rF1b.w; }
    { int r = t >> 4, c = (t & 15) * 4;
      Wf2_s[r * 65 + c] = rF2a.x; Wf2_s[r * 65 + c + 1] = rF2a.y;
      Wf2_s[r * 65 + c + 2] = rF2a.z; Wf2_s[r * 65 + c + 3] = rF2a.w;
      int r2 = (t + 256) >> 4, c2 = ((t + 256) & 15) * 4;
      Wf2_s[r2 * 65 + c2] = rF2b.x; Wf2_s[r2 * 65 + c2 + 1] = rF2b.y;
      Wf2_s[r2 * 65 + c2 + 2] = rF2b.z; Wf2_s[r2 * 65 + c2 + 3] = rF2b.w; }
    { int f = 4 * t, e = f / 96, off = f - e * 96;
      gi_s[e * 97 + off] = rG0.x; gi_s[e * 97 + off + 1] = rG0.y;
      gi_s[e * 97 + off + 2] = rG0.z; gi_s[e * 97 + off + 3] = rG0.w; }
    if (t < 128) {
        int r = t >> 3, c = (t & 7) * 4;
        Ws_s[r * 33 + c] = rWs.x; Ws_s[r * 33 + c + 1] = rWs.y;
        Ws_s[r * 33 + c + 2] = rWs.z; Ws_s[r * 33 + c + 3] = rWs.w;
        We2_s[r * 33 + c] = rE2.x; We2_s[r * 33 + c + 1] = rE2.y;
        We2_s[r * 33 + c + 2] = rE2.z; We2_s[r * 33 + c + 3] = rE2.w;
        int f = 4 * (t + 256), e2 = f / 96, off = f - e2 * 96;
        gi_s[e2 * 97 + off] = rG1.x; gi_s[e2 * 97 + off + 1] = rG1.y;
        gi_s[e2 * 97 + off + 2] = rG1.z; gi_s[e2 * 97 + off + 3] = rG1.w;
    }

    // attn-partial combine + x0 gather (pre-barrier)
    float x0v[4];
    #pragma unroll
    for (int si = 0; si < 4; ++si) {
        const int jj = si * 8 + j0;
        const int ej = jj >> 1;
        const int n = (jj & 1) ? dst[ej] : src[ej];
        const int h = o >> 3, d = o & 7;
        float num = 0.f, den = 0.f;
        #pragma unroll
        for (int ks = 0; ks < 4; ++ks) {
            const float* p = ws + WS_PART + ((jj * 4 + h) * 4 + ks) * 12;
            num += p[d];
            den += p[8];
        }
        arow[jj * 33 + o] = num / den;
        x0v[si] = ws[WS_X0 + n * 32 + o];
    }
    __syncthreads();

    // bookkeeping: prev / round / last (+ maxr) ; slots init for ALL slots
    if (t < 32) {
        const int me = nid_s[t];
        int pv = -1, rd = 0;
        for (int j2 = 0; j2 < t; ++j2) if (nid_s[j2] == me) { pv = j2; ++rd; }
        prev_s[t] = pv; round_s[t] = rd;
        int isl = 1;
        for (int j2 = t + 1; j2 < 32; ++j2) if (nid_s[j2] == me) { isl = 0; break; }
        last_s[t] = isl;
        int mr = rd;
        #pragma unroll
        for (int m = 16; m >= 1; m >>= 1) mr = max(mr, __shfl_xor(mr, m, 32));
        if (t == 0) maxr_s = mr;
    }
    #pragma unroll
    for (int k = 0; k < 4; ++k) {
        int j2 = j0 + 8 * k;
        slots[j2 * 36 + o] = mem[nid_s[j2] * 32 + o];  // nid_s written pre-barrier
    }

    // ---- A1: Wo GEMM + residual + LN1 -> x1s ----
    #pragma unroll
    for (int si = 0; si < 4; ++si) {
        const int jj = si * 8 + j0;
        float a = bias_s[B_BO + o];
        #pragma unroll 8
        for (int i = 0; i < 32; ++i) a += Wo_s[o * 33 + i] * arow[jj * 33 + i];
        float t1 = x0v[si] + a;
        float mu = t1;
        #pragma unroll
        for (int m = 16; m >= 1; m >>= 1) mu += __shfl_xor(mu, m, 32);
        mu *= (1.f / 32.f);
        float dv = t1 - mu;
        float var = dv * dv;
        #pragma unroll
        for (int m = 16; m >= 1; m >>= 1) var += __shfl_xor(var, m, 32);
        var *= (1.f / 32.f);
        x1s[jj * 33 + o] = dv * rsqrtf(var + 1e-5f) * bias_s[B_G1 + o] + bias_s[B_BE1 + o];
    }
    __syncthreads();

    // ---- A2: FFN1 + gelu -> fs ----
    #pragma unroll
    for (int si = 0; si < 4; ++si) {
        const int jj = si * 8 + j0;
        #pragma unroll
        for (int c = 0; c < 2; ++c) {
            int oo = c * 32 + o;
            float f = bias_s[B_BF1 + oo];
            #pragma unroll 8
            for (int i = 0; i < 32; ++i) f += Wf1_s[oo * 33 + i] * x1s[jj * 33 + i];
            fs[jj * 65 + oo] = 0.5f * f * (1.f + erff(f * 0.70710678118654752f));
        }
    }
    __syncthreads();

    // ---- A3: FFN2 + residual + LN2 -> x1s (own element only: race-free) ----
    #pragma unroll
    for (int si = 0; si < 4; ++si) {
        const int jj = si * 8 + j0;
        float f2 = bias_s[B_BF2 + o];
        #pragma unroll 8
        for (int i = 0; i < 64; ++i) f2 += Wf2_s[o * 65 + i] * fs[jj * 65 + i];
        float t2 = x1s[jj * 33 + o] + f2;
        float mu2 = t2;
        #pragma unroll
        for (int m = 16; m >= 1; m >>= 1) mu2 += __shfl_xor(mu2, m, 32);
        mu2 *= (1.f / 32.f);
        float dv2 = t2 - mu2;
        float var2 = dv2 * dv2;
        #pragma unroll
        for (int m = 16; m >= 1; m >>= 1) var2 += __shfl_xor(var2, m, 32);
        var2 *= (1.f / 32.f);
        x1s[jj * 33 + o] = dv2 * rsqrtf(var2 + 1e-5f) * bias_s[B_G2 + o] + bias_s[B_BE2 + o];
    }
    __syncthreads();

    // ---- A4: SCN + LN(16) + relu -> directly into edge-cat layout (arow) ----
    if (o < 16) {
        #pragma unroll
        for (int si = 0; si < 4; ++si) {
            const int jj = si * 8 + j0;
            float sc = bias_s[B_BSCN + o];
            #pragma unroll 8
            for (int i = 0; i < 32; ++i) sc += Ws_s[o * 33 + i] * x1s[jj * 33 + i];
            float m16 = sc;
            #pragma unroll
            for (int m = 8; m >= 1; m >>= 1) m16 += __shfl_xor(m16, m, 16);
            m16 *= (1.f / 16.f);
            float d16 = sc - m16;
            float v16 = d16 * d16;
            #pragma unroll
            for (int m = 8; m >= 1; m >>= 1) v16 += __shfl_xor(v16, m, 16);
            v16 *= (1.f / 16.f);
            float sv = d16 * rsqrtf(v16 + 1e-5f) * bias_s[B_GSCN + o] + bias_s[B_BESCN + o];
            arow[(jj >> 1) * 33 + (jj & 1) * 16 + o] = fmaxf(sv, 0.f);
        }
    }
    __syncthreads();

    // ---- A6: h1 = relu(cat @ We1^T) ----
    #pragma unroll
    for (int k = 0; k < 2; ++k) {
        int e = j0 + 8 * k;
        float acc = bias_s[B_BE1E + o];
        #pragma unroll 8
        for (int i = 0; i < 32; ++i) acc += We1_s[o * 33 + i] * arow[e * 33 + i];
        fs[e * 33 + o] = fmaxf(acc, 0.f);
    }
    __syncthreads();

    // ---- A7: h2 ----
    {
        int e = t >> 4, o2 = t & 15;
        float acc = bias_s[B_BE2E + o2];
        #pragma unroll 8
        for (int i = 0; i < 32; ++i) acc += We2_s[o2 * 33 + i] * fs[e * 33 + i];
        fs[600 + e * 17 + o2] = fmaxf(acc, 0.f);
    }
    __syncthreads();

    // ---- A8: logits ----
    if (t < 16) {
        float acc = bias_s[B_BE3];
        #pragma unroll
        for (int i = 0; i < 16; ++i) acc += bias_s[B_WE3 + i] * fs[600 + t * 17 + i];
        out[t] = acc;
    }

    // ---- PARALLEL GRU scan over dependency rounds ----
    // round r: all slots that are the r-th occurrence of their node (independent).
    // 4 waves x 2 slots each per pass; pass body computes 2 GRUs jointly.
    const int maxr = maxr_s;   // valid: written before a prior barrier
    for (int r = 0; r <= maxr; ++r) {
        if (t < 64) {
            bool act = (t < 32) && (round_s[t] == r);
            unsigned long long mask = __ballot(act);
            if (act) {
                int pos = __popcll(mask & ((1ull << t) - 1ull));
                list_s[pos] = t;
            }
            if (t == 0) cnt_s = (int)__popcll(mask);
        }
        __syncthreads();
        const int cnt = cnt_s;
        for (int pi = w; 2 * pi < cnt; pi += 4) {
            const int sA = list_s[2 * pi];
            const bool doB = (2 * pi + 1 < cnt);
            const int sB = doB ? list_s[2 * pi + 1] : sA;
            const int inA = (prev_s[sA] < 0) ? sA : prev_s[sA];
            const int inB = (prev_s[sB] < 0) ? sB : prev_s[sB];
            float acc1 = b1, acc2 = b2, acc3 = b3;
            #pragma unroll
            for (int c = 0; c < 8; ++c) {
                const float4 hs4 = *(const float4*)&slots[inA * 36 + 4 * c];
                const float4 hd4 = *(const float4*)&slots[inB * 36 + 4 * c];
                acc1 += dot4_(w1[c], hs4);
                const float4 hm = lowhalf ? hs4 : hd4;
                acc2 += dot4_(w2[c], hm);
                acc3 += dot4_(w3[c], hd4);
            }
            const float shv = __shfl_xor(lowhalf ? acc3 : acc1, 32);
            const float hr = lowhalf ? acc1 : acc2;
            const float hz = shv;
            const float hn = lowhalf ? acc2 : acc3;
            const int sX = lowhalf ? sA : sB;
            const int eX = sX >> 1;
            const float ir  = gi_s[eX * 97 + o];
            const float iz  = gi_s[eX * 97 + 32 + o];
            const float inn = gi_s[eX * 97 + 64 + o];
            const float rr = sigmoidf_(ir + hr);
            const float z = sigmoidf_(iz + hz);
            const float nn = tanhf_(inn + rr * hn);
            const float hold = slots[(lowhalf ? inA : inB) * 36 + o];
            const float hnew = (1.f - z) * nn + z * hold;
            if (lowhalf || doB) slots[sX * 36 + o] = hnew;
        }
        __syncthreads();
    }

    // ---- writeback: last occurrence of each node ----
    #pragma unroll
    for (int k = 0; k < 4; ++k) {
        int j2 = j0 + 8 * k;
        if (last_s[j2]) out[16 + nid_s[j2] * 32 + o] = slots[j2 * 36 + o];
    }
}

// ---------------------------------------------------------------------------
extern "C" void kernel_launch(void* const* d_in, const int* in_sizes, int n_in,
                              void* d_out, int out_size, void* d_ws, size_t ws_size,
                              hipStream_t stream)
{
    (void)in_sizes; (void)n_in; (void)out_size; (void)ws_size;
    const int*   src   = (const int*)d_in[0];
    const int*   dst   = (const int*)d_in[1];
    const float* ef    = (const float*)d_in[2];
    const float* nf    = (const float*)d_in[4];
    const float* mem   = (const float*)d_in[6];
    const float* Wemb  = (const float*)d_in[7];
    const float* bemb  = (const float*)d_in[8];
    const float* Wqkv  = (const float*)d_in[9];
    const float* bqkv  = (const float*)d_in[10];
    const float* Wo    = (const float*)d_in[11];
    const float* bo    = (const float*)d_in[12];
    const float* g1    = (const float*)d_in[13];
    const float* be1   = (const float*)d_in[14];
    const float* g2    = (const float*)d_in[15];
    const float* be2   = (const float*)d_in[16];
    const float* Wf1   = (const float*)d_in[17];
    const float* bf1   = (const float*)d_in[18];
    const float* Wf2   = (const float*)d_in[19];
    const float* bf2   = (const float*)d_in[20];
    const float* Wscn  = (const float*)d_in[21];
    const float* bscn  = (const float*)d_in[22];
    const float* gscn  = (const float*)d_in[23];
    const float* bescn = (const float*)d_in[24];
    const float* We1   = (const float*)d_in[25];
    const float* be1e  = (const float*)d_in[26];
    const float* We2   = (const float*)d_in[27];
    const float* be2e  = (const float*)d_in[28];
    const float* We3   = (const float*)d_in[29];
    const float* be3   = (const float*)d_in[30];
    const float* Wih   = (const float*)d_in[31];
    const float* bih   = (const float*)d_in[32];
    const float* Whh   = (const float*)d_in[33];
    const float* bhh   = (const float*)d_in[34];
    const float* Wm1   = (const float*)d_in[35];
    const float* bm1   = (const float*)d_in[36];
    const float* Wm2   = (const float*)d_in[37];
    const float* bm2   = (const float*)d_in[38];
    float* out = (float*)d_out;
    float* ws  = (float*)d_ws;

    hipLaunchKernelGGL(k1_embed_qkv_msg, dim3(256), dim3(256), 0, stream,
        nf, Wemb, bemb, Wqkv, bqkv, mem, src, dst, ef, Wm1, bm1, Wm2, bm2, Wih, bih, ws, out);
    hipLaunchKernelGGL(k2_attn, dim3(128), dim3(256), 0, stream, src, dst, ws);
    hipLaunchKernelGGL(k34_post_scan, dim3(1), dim3(256), 0, stream,
        src, dst, mem, Wo, bo, g1, be1, Wf1, bf1, Wf2, bf2, g2, be2,
        Wscn, bscn, gscn, bescn, Whh, bhh, We1, be1e, We2, be2e, We3, be3, ws, out);
}